// Round 1
// baseline (548.053 us; speedup 1.0000x reference)
//
#include <hip/hip_runtime.h>
#include <math.h>

#define NPTS 8192
#define NB 2
#define KNN 16
#define WPB 4           // waves per block
#define BLOCK (WPB * 64)
#define NROWS (NB * NPTS)

__device__ __forceinline__ float sqd(float ax, float ay, float az,
                                     float bx, float by, float bz) {
  float dx = ax - bx, dy = ay - by, dz = az - bz;
  return fmaf(dx, dx, fmaf(dy, dy, dz * dz));
}

// Maintain ascending sorted list a[0..KNN-1]; insert candidate d if it beats the max.
__device__ __forceinline__ void insert16(float (&a)[KNN], float d) {
  if (d < a[KNN - 1]) {
    a[KNN - 1] = d;
#pragma unroll
    for (int k = KNN - 1; k > 0; --k) {
      float lo = fminf(a[k - 1], a[k]);
      float hi = fmaxf(a[k - 1], a[k]);
      a[k - 1] = lo;
      a[k] = hi;
    }
  }
}

// Merge 64 per-lane ascending KNN-lists into the wave-global smallest-KNN.
// Returns: lane r (r < KNN) holds the r-th smallest value; other lanes 0.
// buf is a per-wave LDS region of 64*KNN floats. Uses __syncthreads(): all
// waves in the block follow identical control flow (uniform trip counts).
__device__ __forceinline__ float wave_merge(const float (&a)[KNN], float* buf, int lane) {
#pragma unroll
  for (int k = 0; k < KNN; ++k) buf[lane * KNN + k] = a[k];
  __syncthreads();
  int h = 0;
  float cur = buf[lane * KNN];
  float res = 0.0f;
  for (int r = 0; r < KNN; ++r) {
    float v = cur;
    int idx = lane;
    // Butterfly argmin with (value, lane) lexicographic tie-break: the pair-min
    // is associative+commutative, so every lane converges to the same winner.
#pragma unroll
    for (int s = 1; s < 64; s <<= 1) {
      float ov = __shfl_xor(v, s);
      int oi = __shfl_xor(idx, s);
      if (ov < v || (ov == v && oi < idx)) { v = ov; idx = oi; }
    }
    if (lane == r) res = v;
    if (lane == idx) {
      ++h;
      cur = (h < KNN) ? buf[lane * KNN + h] : INFINITY;
    }
  }
  __syncthreads();
  return res;
}

// One wave per true point i: top-16 squared distances vs pred and vs true,
// per-row density contribution, and row min (vs pred).
__global__ __launch_bounds__(BLOCK) void rows_kernel(
    const float* __restrict__ yp, const float* __restrict__ yt,
    float* __restrict__ minrow_arr, float* __restrict__ density_arr) {
  __shared__ float smem[WPB][64 * KNN];
  const int wave = threadIdx.x >> 6;
  const int lane = threadIdx.x & 63;
  const int row = blockIdx.x * WPB + wave;  // 0 .. NROWS-1
  const int b = row / NPTS;
  const int i = row - b * NPTS;
  const float* ypB = yp + (size_t)b * NPTS * 3;
  const float* ytB = yt + (size_t)b * NPTS * 3;
  const float tx = ytB[3 * i], ty = ytB[3 * i + 1], tz = ytB[3 * i + 2];

  float aP[KNN], aT[KNN];
#pragma unroll
  for (int k = 0; k < KNN; ++k) { aP[k] = INFINITY; aT[k] = INFINITY; }

  for (int j = lane; j < NPTS; j += 64) {
    float px = ypB[3 * j], py = ypB[3 * j + 1], pz = ypB[3 * j + 2];
    insert16(aP, sqd(tx, ty, tz, px, py, pz));
    float qx = ytB[3 * j], qy = ytB[3 * j + 1], qz = ytB[3 * j + 2];
    insert16(aT, sqd(tx, ty, tz, qx, qy, qz));  // j == i gives 0: diagonal kept, as in ref
  }

  float resP = wave_merge(aP, smem[wave], lane);
  float resT = wave_merge(aT, smem[wave], lane);

  float dpv = (lane < KNN) ? sqrtf(resP) : 0.0f;
  float dtv = (lane < KNN) ? sqrtf(resT) : 0.0f;
  float term = fabsf(dpv - dtv);
#pragma unroll
  for (int s = 1; s < 64; s <<= 1) term += __shfl_xor(term, s);
  if (lane == 0) {
    minrow_arr[row] = sqrtf(resP);  // lane 0 holds the global min (squared)
    density_arr[row] = term;
  }
}

// One wave per pred point j: min squared distance to any true point.
__global__ __launch_bounds__(BLOCK) void cols_kernel(
    const float* __restrict__ yp, const float* __restrict__ yt,
    float* __restrict__ mincol_arr) {
  const int wave = threadIdx.x >> 6;
  const int lane = threadIdx.x & 63;
  const int col = blockIdx.x * WPB + wave;
  const int b = col / NPTS;
  const int j = col - b * NPTS;
  const float* ypB = yp + (size_t)b * NPTS * 3;
  const float* ytB = yt + (size_t)b * NPTS * 3;
  const float px = ypB[3 * j], py = ypB[3 * j + 1], pz = ypB[3 * j + 2];
  float m = INFINITY;
  for (int i = lane; i < NPTS; i += 64) {
    m = fminf(m, sqd(px, py, pz, ytB[3 * i], ytB[3 * i + 1], ytB[3 * i + 2]));
  }
#pragma unroll
  for (int s = 1; s < 64; s <<= 1) m = fminf(m, __shfl_xor(m, s));
  if (lane == 0) mincol_arr[col] = sqrtf(m);
}

// Deterministic single-block reduction of the three per-row arrays -> 3 outputs.
__global__ __launch_bounds__(256) void finalize_kernel(
    const float* __restrict__ minrow_arr, const float* __restrict__ mincol_arr,
    const float* __restrict__ density_arr, float* __restrict__ out) {
  __shared__ double s1[256], s2[256], s3[256];
  const int t = threadIdx.x;
  double a = 0.0, b = 0.0, c = 0.0;
  for (int idx = t; idx < NROWS; idx += 256) {
    a += (double)minrow_arr[idx];
    b += (double)mincol_arr[idx];
    c += (double)density_arr[idx];
  }
  s1[t] = a; s2[t] = b; s3[t] = c;
  __syncthreads();
  for (int off = 128; off > 0; off >>= 1) {
    if (t < off) { s1[t] += s1[t + off]; s2[t] += s2[t + off]; s3[t] += s3[t + off]; }
    __syncthreads();
  }
  if (t == 0) {
    double shape = 0.5 * (s1[0] + s2[0]) / (double)NROWS;
    double dens = s3[0] / ((double)NROWS * KNN);
    out[0] = (float)(shape + dens);  // data_loss
    out[1] = (float)shape;           // shape_loss
    out[2] = (float)dens;            // density_loss
  }
}

extern "C" void kernel_launch(void* const* d_in, const int* in_sizes, int n_in,
                              void* d_out, int out_size, void* d_ws, size_t ws_size,
                              hipStream_t stream) {
  (void)in_sizes; (void)n_in; (void)out_size; (void)ws_size;
  const float* yp = (const float*)d_in[0];  // y_pred [B, N, 3]
  const float* yt = (const float*)d_in[1];  // y_true [B, N, 3]
  float* ws = (float*)d_ws;
  float* minrow_arr = ws;                // NROWS floats
  float* mincol_arr = ws + NROWS;        // NROWS floats
  float* density_arr = ws + 2 * NROWS;   // NROWS floats
  float* out = (float*)d_out;

  rows_kernel<<<NROWS / WPB, BLOCK, 0, stream>>>(yp, yt, minrow_arr, density_arr);
  cols_kernel<<<NROWS / WPB, BLOCK, 0, stream>>>(yp, yt, mincol_arr);
  finalize_kernel<<<1, 256, 0, stream>>>(minrow_arr, mincol_arr, density_arr, out);
}

// Round 2
// 283.485 us; speedup vs baseline: 1.9333x; 1.9333x over previous
//
#include <hip/hip_runtime.h>
#include <math.h>

#define NPTS 8192
#define NB 2
#define NROWS (NB * NPTS)
#define KNN 16
#define G1 8          // rows per wave in pass1 / cols (min-only passes)
#define G2 4          // rows per wave in pass2 (collect pass)
#define TILE 512      // candidate points staged per list per tile
#define CAP 64        // collect capacity per row per list

__device__ __forceinline__ float sqd3(float qx, float qy, float qz, float4 c) {
  float dx = qx - c.x, dy = qy - c.y, dz = qz - c.z;
  return fmaf(dx, dx, fmaf(dy, dy, dz * dz));
}

// Full ascending bitonic sort of one value per lane across the 64-lane wave.
__device__ __forceinline__ float bitonic_sort64(float v, int lane) {
#pragma unroll
  for (int k = 2; k <= 64; k <<= 1) {
#pragma unroll
    for (int j = k >> 1; j >= 1; j >>= 1) {
      float o = __shfl_xor(v, j, 64);
      bool up = ((lane & k) == 0);
      bool lower = ((lane & j) == 0);
      float mn = fminf(v, o), mx = fmaxf(v, o);
      v = (up == lower) ? mn : mx;
    }
  }
  return v;
}

// Pad [N,3] points to float4 for aligned dwordx4 loads.
__global__ __launch_bounds__(256) void repack_kernel(
    const float* __restrict__ yp, const float* __restrict__ yt,
    float4* __restrict__ P4, float4* __restrict__ T4) {
  int i = blockIdx.x * 256 + threadIdx.x;
  if (i < NROWS) {
    P4[i] = make_float4(yp[3 * i], yp[3 * i + 1], yp[3 * i + 2], 0.0f);
    T4[i] = make_float4(yt[3 * i], yt[3 * i + 1], yt[3 * i + 2], 0.0f);
  }
}

// Pass 1: per row (true point): per-lane min over its 128 candidates, for both
// candidate lists. Sorted lane-minima give exact minrow (lane 0) and a provable
// 16-NN upper bound tau (lane 15: 16 distinct candidates are <= it).
__global__ __launch_bounds__(256) void pass1_kernel(
    const float4* __restrict__ P4, const float4* __restrict__ T4,
    float* __restrict__ tauP, float* __restrict__ tauT,
    float* __restrict__ minrow_arr) {
  const int wave = threadIdx.x >> 6, lane = threadIdx.x & 63;
  const int w = blockIdx.x * 4 + wave;
  const int r0 = w * G1;
  const int b = r0 >> 13;
  const int i0 = r0 & (NPTS - 1);
  const float4* Pb = P4 + ((size_t)b << 13);
  const float4* Tb = T4 + ((size_t)b << 13);
  float qx[G1], qy[G1], qz[G1], mP[G1], mT[G1];
#pragma unroll
  for (int r = 0; r < G1; ++r) {
    float4 q = Tb[i0 + r];
    qx[r] = q.x; qy[r] = q.y; qz[r] = q.z;
    mP[r] = INFINITY; mT[r] = INFINITY;
  }
  for (int s = 0; s < NPTS / 64; ++s) {
    float4 c = Pb[s * 64 + lane];
#pragma unroll
    for (int r = 0; r < G1; ++r) mP[r] = fminf(mP[r], sqd3(qx[r], qy[r], qz[r], c));
    float4 c2 = Tb[s * 64 + lane];
#pragma unroll
    for (int r = 0; r < G1; ++r) mT[r] = fminf(mT[r], sqd3(qx[r], qy[r], qz[r], c2));
  }
#pragma unroll 1
  for (int r = 0; r < G1; ++r) {
    float v = bitonic_sort64(mP[r], lane);
    if (lane == 0) minrow_arr[r0 + r] = sqrtf(v);   // exact global min (squared->sqrt)
    if (lane == 15) tauP[r0 + r] = v;               // 16th smallest lane-min
    float v2 = bitonic_sort64(mT[r], lane);
    if (lane == 15) tauT[r0 + r] = v2;
  }
}

// mincol: per pred point, min distance to any true point (same structure).
__global__ __launch_bounds__(256) void cols_kernel(
    const float4* __restrict__ P4, const float4* __restrict__ T4,
    float* __restrict__ mincol_arr) {
  const int wave = threadIdx.x >> 6, lane = threadIdx.x & 63;
  const int w = blockIdx.x * 4 + wave;
  const int c0 = w * G1;
  const int b = c0 >> 13;
  const int j0 = c0 & (NPTS - 1);
  const float4* Pb = P4 + ((size_t)b << 13);
  const float4* Tb = T4 + ((size_t)b << 13);
  float qx[G1], qy[G1], qz[G1], m[G1];
#pragma unroll
  for (int r = 0; r < G1; ++r) {
    float4 q = Pb[j0 + r];
    qx[r] = q.x; qy[r] = q.y; qz[r] = q.z;
    m[r] = INFINITY;
  }
  for (int s = 0; s < NPTS / 64; ++s) {
    float4 c = Tb[s * 64 + lane];
#pragma unroll
    for (int r = 0; r < G1; ++r) m[r] = fminf(m[r], sqd3(qx[r], qy[r], qz[r], c));
  }
#pragma unroll 1
  for (int r = 0; r < G1; ++r) {
    float v = m[r];
#pragma unroll
    for (int s = 1; s < 64; s <<= 1) v = fminf(v, __shfl_xor(v, s, 64));
    if (lane == 0) mincol_arr[c0 + r] = sqrtf(v);
  }
}

// Guaranteed-exact fallback: per-lane sorted-16 insert over the full list, then
// 16 rounds of wave argmin extraction (register-only merge). Returns lane r's
// r-th smallest squared distance (r < 16); INF elsewhere. Never fires in
// practice (needs >CAP candidates under tau).
__device__ float exact16_rowlist(const float4* __restrict__ base,
                                 float qx, float qy, float qz, int lane) {
  float a[KNN];
#pragma unroll
  for (int k = 0; k < KNN; ++k) a[k] = INFINITY;
  for (int s = 0; s < NPTS / 64; ++s) {
    float d = sqd3(qx, qy, qz, base[s * 64 + lane]);
    if (d < a[KNN - 1]) {
      a[KNN - 1] = d;
#pragma unroll
      for (int k = KNN - 1; k > 0; --k) {
        float lo = fminf(a[k - 1], a[k]);
        float hi = fmaxf(a[k - 1], a[k]);
        a[k - 1] = lo; a[k] = hi;
      }
    }
  }
  float res = INFINITY;
#pragma unroll 1
  for (int r = 0; r < KNN; ++r) {
    float v = a[0];
    int idx = lane;
#pragma unroll
    for (int s = 1; s < 64; s <<= 1) {
      float ov = __shfl_xor(v, s, 64);
      int oi = __shfl_xor(idx, s, 64);
      bool take = (ov < v) || (ov == v && oi < idx);
      v = take ? ov : v;
      idx = take ? oi : idx;
    }
    if (lane == r) res = v;
    if (lane == idx) {  // winner advances its list (static indices only)
#pragma unroll
      for (int k = 0; k < KNN - 1; ++k) a[k] = a[k + 1];
      a[KNN - 1] = INFINITY;
    }
  }
  return res;
}

// Pass 2: collect all candidates with d <= tau per row per list (LDS-tiled
// candidates, G2 rows/wave), then one bitonic sort-64 -> exact ascending 16-NN
// of both lists; positional |sqrt-sqrt| sum is the row's density contribution.
__global__ __launch_bounds__(256) void knn_kernel(
    const float4* __restrict__ P4, const float4* __restrict__ T4,
    const float* __restrict__ tauP, const float* __restrict__ tauT,
    float* __restrict__ density_arr) {
  __shared__ float4 tile[2 * TILE];       // 16 KB: P tile then T tile
  __shared__ float col[16][2][CAP];       // 8 KB collect buffers
  __shared__ int cnt[16][2];
  const int wave = threadIdx.x >> 6, lane = threadIdx.x & 63;
  const int row0 = blockIdx.x * 16;       // 16 rows per block
  const int b = row0 >> 13;
  const int i0 = row0 & (NPTS - 1);
  const float4* Pb = P4 + ((size_t)b << 13);
  const float4* Tb = T4 + ((size_t)b << 13);
  const int wr0 = wave * G2;
  float qx[G2], qy[G2], qz[G2], tP[G2], tT[G2];
#pragma unroll
  for (int r = 0; r < G2; ++r) {
    float4 q = Tb[i0 + wr0 + r];
    qx[r] = q.x; qy[r] = q.y; qz[r] = q.z;
    tP[r] = tauP[row0 + wr0 + r];
    tT[r] = tauT[row0 + wr0 + r];
  }
  if (threadIdx.x < 32) cnt[threadIdx.x >> 1][threadIdx.x & 1] = 0;
  __syncthreads();
  for (int t = 0; t < NPTS / TILE; ++t) {
    for (int u = threadIdx.x; u < TILE; u += 256) {
      tile[u] = Pb[t * TILE + u];
      tile[TILE + u] = Tb[t * TILE + u];
    }
    __syncthreads();
    for (int s = 0; s < TILE / 64; ++s) {
      float4 c = tile[s * 64 + lane];
#pragma unroll
      for (int r = 0; r < G2; ++r) {
        float d = sqd3(qx[r], qy[r], qz[r], c);
        if (d <= tP[r]) {                 // rare: ~20 of 8192 candidates pass
          int ix = atomicAdd(&cnt[wr0 + r][0], 1);
          if (ix < CAP) col[wr0 + r][0][ix] = d;
        }
      }
      float4 c2 = tile[TILE + s * 64 + lane];
#pragma unroll
      for (int r = 0; r < G2; ++r) {
        float d = sqd3(qx[r], qy[r], qz[r], c2);
        if (d <= tT[r]) {
          int ix = atomicAdd(&cnt[wr0 + r][1], 1);
          if (ix < CAP) col[wr0 + r][1][ix] = d;
        }
      }
    }
    __syncthreads();
  }
#pragma unroll 1
  for (int r = 0; r < G2; ++r) {
    int cP = cnt[wr0 + r][0];
    int cT = cnt[wr0 + r][1];
    float vP = (lane < cP && lane < CAP) ? col[wr0 + r][0][lane] : INFINITY;
    float vT = (lane < cT && lane < CAP) ? col[wr0 + r][1][lane] : INFINITY;
    float sP = bitonic_sort64(vP, lane);
    float sT = bitonic_sort64(vT, lane);
    if (cP > CAP) sP = exact16_rowlist(Pb, qx[r], qy[r], qz[r], lane);  // never in practice
    if (cT > CAP) sT = exact16_rowlist(Tb, qx[r], qy[r], qz[r], lane);
    float term = (lane < KNN) ? fabsf(sqrtf(sP) - sqrtf(sT)) : 0.0f;
#pragma unroll
    for (int s = 1; s < 64; s <<= 1) term += __shfl_xor(term, s, 64);
    if (lane == 0) density_arr[row0 + wr0 + r] = term;
  }
}

// Deterministic single-block reduction -> 3 outputs.
__global__ __launch_bounds__(256) void finalize_kernel(
    const float* __restrict__ minrow_arr, const float* __restrict__ mincol_arr,
    const float* __restrict__ density_arr, float* __restrict__ out) {
  __shared__ double s1[256], s2[256], s3[256];
  const int t = threadIdx.x;
  double a = 0.0, b = 0.0, c = 0.0;
  for (int idx = t; idx < NROWS; idx += 256) {
    a += (double)minrow_arr[idx];
    b += (double)mincol_arr[idx];
    c += (double)density_arr[idx];
  }
  s1[t] = a; s2[t] = b; s3[t] = c;
  __syncthreads();
  for (int off = 128; off > 0; off >>= 1) {
    if (t < off) { s1[t] += s1[t + off]; s2[t] += s2[t + off]; s3[t] += s3[t + off]; }
    __syncthreads();
  }
  if (t == 0) {
    double shape = 0.5 * (s1[0] + s2[0]) / (double)NROWS;
    double dens = s3[0] / ((double)NROWS * KNN);
    out[0] = (float)(shape + dens);  // data_loss
    out[1] = (float)shape;           // shape_loss
    out[2] = (float)dens;            // density_loss
  }
}

extern "C" void kernel_launch(void* const* d_in, const int* in_sizes, int n_in,
                              void* d_out, int out_size, void* d_ws, size_t ws_size,
                              hipStream_t stream) {
  (void)in_sizes; (void)n_in; (void)out_size; (void)ws_size;
  const float* yp = (const float*)d_in[0];  // y_pred [B, N, 3]
  const float* yt = (const float*)d_in[1];  // y_true [B, N, 3]
  float* ws = (float*)d_ws;
  float4* P4 = (float4*)ws;                          // NROWS float4
  float4* T4 = (float4*)(ws + 4 * NROWS);            // NROWS float4
  float* tauP = ws + 8 * NROWS;                      // NROWS
  float* tauT = tauP + NROWS;
  float* minrow_arr = tauT + NROWS;
  float* mincol_arr = minrow_arr + NROWS;
  float* density_arr = mincol_arr + NROWS;
  float* out = (float*)d_out;

  repack_kernel<<<NROWS / 256, 256, 0, stream>>>(yp, yt, P4, T4);
  pass1_kernel<<<NROWS / (G1 * 4), 256, 0, stream>>>(P4, T4, tauP, tauT, minrow_arr);
  cols_kernel<<<NROWS / (G1 * 4), 256, 0, stream>>>(P4, T4, mincol_arr);
  knn_kernel<<<NROWS / 16, 256, 0, stream>>>(P4, T4, tauP, tauT, density_arr);
  finalize_kernel<<<1, 256, 0, stream>>>(minrow_arr, mincol_arr, density_arr, out);
}

// Round 3
// 211.807 us; speedup vs baseline: 2.5875x; 1.3384x over previous
//
#include <hip/hip_runtime.h>
#include <math.h>

#define NPTS 8192
#define NB 2
#define NROWS (NB * NPTS)
#define KNN 16
#define CAP 64        // collect capacity per row per list

// pass1 geometry: 1024-thread blocks, 16 waves x 4 rows = 64 rows/block
#define P1_G 4
#define P1_WAVES 16
#define P1_ROWS (P1_WAVES * P1_G)          // 64
#define P1_BLOCKS (NROWS / P1_ROWS)        // 256
#define P1_PER_BATCH (P1_BLOCKS / NB)      // 128

// knn geometry: 256-thread blocks, 4 waves x 2 rows = 8 rows/block
#define K_G 2
#define K_ROWS 8
#define K_BLOCKS (NROWS / K_ROWS)          // 2048

#define INF_BITS 0x7F800000u

__device__ __forceinline__ float sqd3(float qx, float qy, float qz, float4 c) {
  float dx = qx - c.x, dy = qy - c.y, dz = qz - c.z;
  return fmaf(dx, dx, fmaf(dy, dy, dz * dz));
}

// Full ascending bitonic sort of one value per lane across the 64-lane wave.
__device__ __forceinline__ float bitonic_sort64(float v, int lane) {
#pragma unroll
  for (int k = 2; k <= 64; k <<= 1) {
#pragma unroll
    for (int j = k >> 1; j >= 1; j >>= 1) {
      float o = __shfl_xor(v, j, 64);
      bool up = ((lane & k) == 0);
      bool lower = ((lane & j) == 0);
      float mn = fminf(v, o), mx = fmaxf(v, o);
      v = (up == lower) ? mn : mx;
    }
  }
  return v;
}

// Pad [N,3] points to float4 for aligned dwordx4 loads.
__global__ __launch_bounds__(256) void repack_kernel(
    const float* __restrict__ yp, const float* __restrict__ yt,
    float4* __restrict__ P4, float4* __restrict__ T4) {
  int i = blockIdx.x * 256 + threadIdx.x;
  if (i < NROWS) {
    P4[i] = make_float4(yp[3 * i], yp[3 * i + 1], yp[3 * i + 2], 0.0f);
    T4[i] = make_float4(yt[3 * i], yt[3 * i + 1], yt[3 * i + 2], 0.0f);
  }
}

// Pass 1: per true-point row, per-lane min over 128 candidates for both lists
// (sorted lane-minima -> exact minrow + provable 16-NN bound tau), AND the
// column-min (mincol) rides along: per (lane,step) candidate j, min over the
// wave's 4 rows -> LDS atomicMin -> per-block partial written to ws.
__global__ __launch_bounds__(1024) void pass1_kernel(
    const float4* __restrict__ P4, const float4* __restrict__ T4,
    float* __restrict__ tauP, float* __restrict__ tauT,
    float* __restrict__ minrow_arr, unsigned* __restrict__ colmin_part) {
  __shared__ unsigned colmin[NPTS];   // 32 KB, uint bits of nonneg float
  const int wave = threadIdx.x >> 6, lane = threadIdx.x & 63;
  const int r0 = blockIdx.x * P1_ROWS + wave * P1_G;
  const int b = r0 >> 13;
  const int i0 = r0 & (NPTS - 1);
  const float4* Pb = P4 + ((size_t)b << 13);
  const float4* Tb = T4 + ((size_t)b << 13);

  for (int u = threadIdx.x; u < NPTS; u += 1024) colmin[u] = INF_BITS;

  float qx[P1_G], qy[P1_G], qz[P1_G], mP[P1_G], mT[P1_G];
#pragma unroll
  for (int r = 0; r < P1_G; ++r) {
    float4 q = Tb[i0 + r];
    qx[r] = q.x; qy[r] = q.y; qz[r] = q.z;
    mP[r] = INFINITY; mT[r] = INFINITY;
  }
  __syncthreads();

  float4 cP = Pb[lane], cT = Tb[lane];
  for (int s = 0; s < NPTS / 64; ++s) {
    int sn = (s + 1) & (NPTS / 64 - 1);
    float4 nP = Pb[sn * 64 + lane];        // prefetch next step
    float4 nT = Tb[sn * 64 + lane];
    float dP[P1_G];
#pragma unroll
    for (int r = 0; r < P1_G; ++r) {
      dP[r] = sqd3(qx[r], qy[r], qz[r], cP);
      mP[r] = fminf(mP[r], dP[r]);
    }
    float cm = fminf(fminf(dP[0], dP[1]), fminf(dP[2], dP[3]));
    atomicMin(&colmin[s * 64 + lane], __float_as_uint(cm));  // 2 lanes/bank: free
#pragma unroll
    for (int r = 0; r < P1_G; ++r) mT[r] = fminf(mT[r], sqd3(qx[r], qy[r], qz[r], cT));
    cP = nP; cT = nT;
  }
  __syncthreads();

  // block-partial column minima -> ws
  unsigned* part = colmin_part + (size_t)blockIdx.x * NPTS;
  for (int u = threadIdx.x; u < NPTS; u += 1024) part[u] = colmin[u];

  // per-row epilogue: sort 64 lane-minima
#pragma unroll 1
  for (int r = 0; r < P1_G; ++r) {
    float v = bitonic_sort64(mP[r], lane);
    if (lane == 0) minrow_arr[r0 + r] = sqrtf(v);   // exact global min
    if (lane == 15) tauP[r0 + r] = v;               // 16th-smallest lane-min
    float v2 = bitonic_sort64(mT[r], lane);
    if (lane == 15) tauT[r0 + r] = v2;
  }
}

// Combine the 128 per-block column-min partials per batch -> mincol.
__global__ __launch_bounds__(256) void colmin_combine_kernel(
    const unsigned* __restrict__ colmin_part, float* __restrict__ mincol_arr) {
  int idx = blockIdx.x * 256 + threadIdx.x;      // 0 .. NROWS-1
  int b = idx >> 13, j = idx & (NPTS - 1);
  const unsigned* base = colmin_part + (size_t)b * P1_PER_BATCH * NPTS + j;
  unsigned m = INF_BITS;
#pragma unroll 4
  for (int p = 0; p < P1_PER_BATCH; ++p) m = min(m, base[(size_t)p * NPTS]);
  mincol_arr[idx] = sqrtf(__uint_as_float(m));
}

// Guaranteed-exact fallback (fires only if >CAP candidates under tau; P~0).
__device__ float exact16_rowlist(const float4* __restrict__ base,
                                 float qx, float qy, float qz, int lane) {
  float a[KNN];
#pragma unroll
  for (int k = 0; k < KNN; ++k) a[k] = INFINITY;
  for (int s = 0; s < NPTS / 64; ++s) {
    float d = sqd3(qx, qy, qz, base[s * 64 + lane]);
    if (d < a[KNN - 1]) {
      a[KNN - 1] = d;
#pragma unroll
      for (int k = KNN - 1; k > 0; --k) {
        float lo = fminf(a[k - 1], a[k]);
        float hi = fmaxf(a[k - 1], a[k]);
        a[k - 1] = lo; a[k] = hi;
      }
    }
  }
  float res = INFINITY;
#pragma unroll 1
  for (int r = 0; r < KNN; ++r) {
    float v = a[0];
    int idx = lane;
#pragma unroll
    for (int s = 1; s < 64; s <<= 1) {
      float ov = __shfl_xor(v, s, 64);
      int oi = __shfl_xor(idx, s, 64);
      bool take = (ov < v) || (ov == v && oi < idx);
      v = take ? ov : v;
      idx = take ? oi : idx;
    }
    if (lane == r) res = v;
    if (lane == idx) {
#pragma unroll
      for (int k = 0; k < KNN - 1; ++k) a[k] = a[k + 1];
      a[KNN - 1] = INFINITY;
    }
  }
  return res;
}

// Pass 2: collect candidates with d <= tau per row per list (direct L2 reads,
// wave-private LDS, zero barriers), one bitonic sort-64 -> exact ascending
// 16-NN of both lists -> positional |sqrt-sqrt| density contribution.
__global__ __launch_bounds__(256) void knn_kernel(
    const float4* __restrict__ P4, const float4* __restrict__ T4,
    const float* __restrict__ tauP, const float* __restrict__ tauT,
    float* __restrict__ density_arr) {
  __shared__ float col[K_ROWS][2][CAP];   // 4 KB
  __shared__ int cnt[K_ROWS][2];
  const int wave = threadIdx.x >> 6, lane = threadIdx.x & 63;
  const int row0 = blockIdx.x * K_ROWS;
  const int b = row0 >> 13;
  const int i0 = row0 & (NPTS - 1);
  const float4* Pb = P4 + ((size_t)b << 13);
  const float4* Tb = T4 + ((size_t)b << 13);
  const int wr = wave * K_G;

  if (lane < 2 * K_G) cnt[wr + (lane >> 1)][lane & 1] = 0;  // wave-private init

  float qx[K_G], qy[K_G], qz[K_G], tP[K_G], tT[K_G];
#pragma unroll
  for (int r = 0; r < K_G; ++r) {
    float4 q = Tb[i0 + wr + r];
    qx[r] = q.x; qy[r] = q.y; qz[r] = q.z;
    tP[r] = tauP[row0 + wr + r];
    tT[r] = tauT[row0 + wr + r];
  }

  float4 cP = Pb[lane], cT = Tb[lane];
  for (int s = 0; s < NPTS / 64; ++s) {
    int sn = (s + 1) & (NPTS / 64 - 1);
    float4 nP = Pb[sn * 64 + lane];
    float4 nT = Tb[sn * 64 + lane];
#pragma unroll
    for (int r = 0; r < K_G; ++r) {
      float d = sqd3(qx[r], qy[r], qz[r], cP);
      if (d <= tP[r]) {                    // ~20 of 8192 pass
        int ix = atomicAdd(&cnt[wr + r][0], 1);
        if (ix < CAP) col[wr + r][0][ix] = d;
      }
    }
#pragma unroll
    for (int r = 0; r < K_G; ++r) {
      float d = sqd3(qx[r], qy[r], qz[r], cT);
      if (d <= tT[r]) {
        int ix = atomicAdd(&cnt[wr + r][1], 1);
        if (ix < CAP) col[wr + r][1][ix] = d;
      }
    }
    cP = nP; cT = nT;
  }

#pragma unroll 1
  for (int r = 0; r < K_G; ++r) {
    int cPc = cnt[wr + r][0];
    int cTc = cnt[wr + r][1];
    float vP = (lane < cPc) ? col[wr + r][0][lane] : INFINITY;
    float vT = (lane < cTc) ? col[wr + r][1][lane] : INFINITY;
    float sP = bitonic_sort64(vP, lane);
    float sT = bitonic_sort64(vT, lane);
    if (cPc > CAP) sP = exact16_rowlist(Pb, qx[r], qy[r], qz[r], lane);
    if (cTc > CAP) sT = exact16_rowlist(Tb, qx[r], qy[r], qz[r], lane);
    float term = (lane < KNN) ? fabsf(sqrtf(sP) - sqrtf(sT)) : 0.0f;
#pragma unroll
    for (int s = 1; s < 64; s <<= 1) term += __shfl_xor(term, s, 64);
    if (lane == 0) density_arr[row0 + wr + r] = term;
  }
}

// Deterministic single-block reduction -> 3 outputs.
__global__ __launch_bounds__(256) void finalize_kernel(
    const float* __restrict__ minrow_arr, const float* __restrict__ mincol_arr,
    const float* __restrict__ density_arr, float* __restrict__ out) {
  __shared__ double s1[256], s2[256], s3[256];
  const int t = threadIdx.x;
  double a = 0.0, b = 0.0, c = 0.0;
  for (int idx = t; idx < NROWS; idx += 256) {
    a += (double)minrow_arr[idx];
    b += (double)mincol_arr[idx];
    c += (double)density_arr[idx];
  }
  s1[t] = a; s2[t] = b; s3[t] = c;
  __syncthreads();
  for (int off = 128; off > 0; off >>= 1) {
    if (t < off) { s1[t] += s1[t + off]; s2[t] += s2[t + off]; s3[t] += s3[t + off]; }
    __syncthreads();
  }
  if (t == 0) {
    double shape = 0.5 * (s1[0] + s2[0]) / (double)NROWS;
    double dens = s3[0] / ((double)NROWS * KNN);
    out[0] = (float)(shape + dens);  // data_loss
    out[1] = (float)shape;           // shape_loss
    out[2] = (float)dens;            // density_loss
  }
}

extern "C" void kernel_launch(void* const* d_in, const int* in_sizes, int n_in,
                              void* d_out, int out_size, void* d_ws, size_t ws_size,
                              hipStream_t stream) {
  (void)in_sizes; (void)n_in; (void)out_size; (void)ws_size;
  const float* yp = (const float*)d_in[0];  // y_pred [B, N, 3]
  const float* yt = (const float*)d_in[1];  // y_true [B, N, 3]
  float* ws = (float*)d_ws;
  float4* P4 = (float4*)ws;                           // NROWS float4
  float4* T4 = (float4*)(ws + 4 * NROWS);             // NROWS float4
  float* tauP = ws + 8 * NROWS;                       // NROWS
  float* tauT = tauP + NROWS;
  float* minrow_arr = tauT + NROWS;
  float* mincol_arr = minrow_arr + NROWS;
  float* density_arr = mincol_arr + NROWS;
  unsigned* colmin_part = (unsigned*)(density_arr + NROWS);  // P1_BLOCKS*NPTS u32 (8 MB)
  float* out = (float*)d_out;

  repack_kernel<<<NROWS / 256, 256, 0, stream>>>(yp, yt, P4, T4);
  pass1_kernel<<<P1_BLOCKS, 1024, 0, stream>>>(P4, T4, tauP, tauT, minrow_arr, colmin_part);
  colmin_combine_kernel<<<NROWS / 256, 256, 0, stream>>>(colmin_part, mincol_arr);
  knn_kernel<<<K_BLOCKS, 256, 0, stream>>>(P4, T4, tauP, tauT, density_arr);
  finalize_kernel<<<1, 256, 0, stream>>>(minrow_arr, mincol_arr, density_arr, out);
}